// Round 1
// baseline (128.871 us; speedup 1.0000x reference)
//
#include <hip/hip_runtime.h>

typedef __attribute__((ext_vector_type(8))) short short8;
typedef __attribute__((ext_vector_type(4))) float f32x4;
typedef __attribute__((ext_vector_type(4))) unsigned uint4v;

#define DIN 512
#define DOUT 128
#define KK 16
#define BTOT 8192
#define KAUG (DIN * KK + DIN)        // 8704 augmented K (spline 8192 + skip 512)
#define NCHUNK_TOT (KAUG / 128)      // 68 chunks of BK=128
#define NSPL 4                       // split-K factor
#define CPB (NCHUNK_TOT / NSPL)      // 17 chunks per block
#define BM 64                        // b-rows per block
#define CHUNK_BYTES 32768            // W chunk: 128 o x 128 k x bf16
#define LDS_BYTES 65536              // double-buffered W chunk only (A built in regs)

// round-to-nearest-even fp32 -> bf16
__device__ static inline unsigned short f2bf(float x) {
  unsigned u = __builtin_bit_cast(unsigned, x);
  return (unsigned short)((u + 0x7FFFu + ((u >> 16) & 1u)) >> 16);
}

// async global->LDS, 16B per lane (dst = wave-uniform base + lane*16)
__device__ static inline void llds16(const char* g, char* l) {
  __builtin_amdgcn_global_load_lds(
      (const __attribute__((address_space(1))) unsigned int*)g,
      (__attribute__((address_space(3))) unsigned int*)l, 16, 0, 0);
}

// Build one MFMA A-granule (8 bf16 = slots [half*8, half*8+8) of one input dim)
// of hat-basis coefficients for value xv, entirely in registers.
// Nonzeros: h0=bf16(1-f) at slot i0, h1=bf16(f) at slot i0+1 (i0<=14).
__device__ static inline short8 spline_granule(float xv, int half) {
  float t = fminf(fmaxf((xv + 3.0f) * (1.0f / 6.0f), 0.0f), 1.0f);
  float pos = t * 15.0f;
  int i0 = (int)pos;
  i0 = i0 > 14 ? 14 : i0;
  float f = pos - (float)i0;
  unsigned h0 = f2bf(1.0f - f);
  unsigned h1 = f2bf(f);
  // P = [h1:h0] as a 32-bit pair; place at short-position j0 of the 128-bit granule
  unsigned long long P = (unsigned long long)(h0 | ((unsigned)h1 << 16));
  const int j0 = i0 - (half << 3);          // -8..14; valid content iff -1..7
  const unsigned ju = (unsigned)j0;
  unsigned long long Pl = P << ((j0 & 3) << 4);
  unsigned long long spill = P >> 16;       // h1 alone (crossing a 64-bit boundary)
  unsigned long long lo = (ju < 4u) ? Pl : ((j0 == -1) ? spill : 0ULL);
  unsigned long long hi = ((ju - 4u) < 4u) ? Pl : ((j0 == 3) ? spill : 0ULL);
  struct U { unsigned long long a, b; } u{lo, hi};
  return __builtin_bit_cast(short8, u);
}

// pack 8 fp32 -> 8 bf16
__device__ static inline short8 pack8(float4 a, float4 b) {
  uint4v p;
  p.x = f2bf(a.x) | ((unsigned)f2bf(a.y) << 16);
  p.y = f2bf(a.z) | ((unsigned)f2bf(a.w) << 16);
  p.z = f2bf(b.x) | ((unsigned)f2bf(b.y) << 16);
  p.w = f2bf(b.z) | ((unsigned)f2bf(b.w) << 16);
  return __builtin_bit_cast(short8, p);
}

// ---------------- prep: pack W_aug into swizzled bf16 chunk image ----------------
// (unchanged) W''[g][o][kcs] granules of 16B (8 bf16), kcs = kc ^ (o&15)
__global__ __launch_bounds__(256) void build_wpp(const float* __restrict__ w,
                                                 const float* __restrict__ sk,
                                                 unsigned short* __restrict__ wpp) {
  const int gi = blockIdx.x * 256 + threadIdx.x;
  const int g = gi >> 11;
  const int rem = gi & 2047;
  const int o = rem >> 4;
  const int kcs = rem & 15;
  const int kc = kcs ^ (o & 15);
  const int kglob = g * 128 + kc * 8;
  const float* src = (kglob < 8192) ? (w + (size_t)o * 8192 + kglob)
                                    : (sk + (size_t)o * 512 + (kglob - 8192));
  const float4 v0 = ((const float4*)src)[0];
  const float4 v1 = ((const float4*)src)[1];
  uint4 pk;
  pk.x = f2bf(v0.x) | ((unsigned)f2bf(v0.y) << 16);
  pk.y = f2bf(v0.z) | ((unsigned)f2bf(v0.w) << 16);
  pk.z = f2bf(v1.x) | ((unsigned)f2bf(v1.y) << 16);
  pk.w = f2bf(v1.z) | ((unsigned)f2bf(v1.w) << 16);
  ((uint4*)wpp)[gi] = pk;
}

// ---------------- main: register-built A + double-buffered W GEMM ----------------
// grid 512 = 128 b-tiles x 4 k-splits; block 256 (4 waves, wave-tile 32x64)
// Per chunk (one barrier): [skip-x loads] -> stage W(c+1) -> prefetch x(c+1)
//   -> build A-frags(c) in regs -> B ds_reads + 32 MFMA -> __syncthreads (full drain).
// Stage/x latency is hidden under one full chunk of compute; A never touches LDS.
__global__ __launch_bounds__(256, 2) void kan_mfma(const float* __restrict__ x,
                                                   const unsigned short* __restrict__ wpp,
                                                   const float* __restrict__ bias,
                                                   float* __restrict__ out) {
  __shared__ __align__(16) char smem[LDS_BYTES];
  const int tid = threadIdx.x;
  const int bt = blockIdx.x >> 2;
  const int sp = blockIdx.x & 3;
  const int b0 = bt * BM;
  const int wid = tid >> 6, lane = tid & 63;
  const int lr = lane & 15, lq = lane >> 4;
  const int wm = wid & 1, wn = wid >> 1;
  const int g0 = sp * CPB;

  f32x4 acc[2][4] = {};

  // per-lane x row pointers for the two m-tiles (fixed across chunks)
  const float* xr0 = x + (size_t)(b0 + wm * 32 + lr) * DIN;
  const float* xr1 = xr0 + 16 * DIN;

  // prologue: stage chunk 0 into buf0, prefetch x for chunk 0 (g0<=51 -> spline)
  {
    const char* gsrc = (const char*)wpp + (size_t)g0 * CHUNK_BYTES + wid * 8192 + lane * 16;
    char* ldst = smem + wid * 8192;
#pragma unroll
    for (int it = 0; it < 8; ++it) llds16(gsrc + it * 1024, ldst + it * 1024);
  }
  float xvA[2][4], xvB[2][4];
  {
    const int ib = g0 * 8 + (lq >> 1);
#pragma unroll
    for (int ks = 0; ks < 4; ++ks) {
      xvA[0][ks] = xr0[ib + ks * 2];
      xvA[1][ks] = xr1[ib + ks * 2];
    }
  }
  __syncthreads();  // drains stage(0) + x(0)

  // chunk body; cb = current LDS buffer byte offset (compile-time 0/32768 per site);
  // xcur/xnxt rotate by reference so all indexing stays compile-time (no scratch).
  auto chunk_body = [&](int c, int cb, float (&xcur)[2][4], float (&xnxt)[2][4]) {
    const int g = g0 + c;
    const bool haveNext = (c + 1 < CPB);

    // skip-augmented chunks (g>=64, only in sp==3 tail): raw x loads, issued
    // BEFORE the stage so their wait leaves the stage in flight
    float4 r0[4][2], r1[4][2];
    if (g >= 64) {
      const int koff = (g - 64) * 128 + lq * 8;
#pragma unroll
      for (int ks = 0; ks < 4; ++ks) {
        r0[ks][0] = ((const float4*)(xr0 + koff + ks * 32))[0];
        r0[ks][1] = ((const float4*)(xr0 + koff + ks * 32))[1];
        r1[ks][0] = ((const float4*)(xr1 + koff + ks * 32))[0];
        r1[ks][1] = ((const float4*)(xr1 + koff + ks * 32))[1];
      }
    }

    // stage W chunk c+1 into the other buffer (lands by end-of-chunk barrier)
    if (haveNext) {
      const char* gsrc = (const char*)wpp + (size_t)(g + 1) * CHUNK_BYTES + wid * 8192 + lane * 16;
      char* ldst = smem + (cb ^ 32768) + wid * 8192;
#pragma unroll
      for (int it = 0; it < 8; ++it) llds16(gsrc + it * 1024, ldst + it * 1024);
    }
    // prefetch x for chunk c+1 (spline chunks only)
    if (haveNext && (g + 1 < 64)) {
      const int ib = (g + 1) * 8 + (lq >> 1);
#pragma unroll
      for (int ks = 0; ks < 4; ++ks) {
        xnxt[0][ks] = xr0[ib + ks * 2];
        xnxt[1][ks] = xr1[ib + ks * 2];
      }
    }

    // ---- A fragments in registers ----
    // lane (lr,lq) granule for kstep ks: k = (ks*4+lq)*8.. -> i = g*8+ks*2+(lq>>1),
    // half = lq&1 (slots 0-7 / 8-15)
    short8 af[2][4];
    if (g < 64) {
      const int half = lq & 1;
#pragma unroll
      for (int ks = 0; ks < 4; ++ks) {
        af[0][ks] = spline_granule(xcur[0][ks], half);
        af[1][ks] = spline_granule(xcur[1][ks], half);
      }
    } else {
#pragma unroll
      for (int ks = 0; ks < 4; ++ks) {
        af[0][ks] = pack8(r0[ks][0], r0[ks][1]);
        af[1][ks] = pack8(r1[ks][0], r1[ks][1]);
      }
    }

    // ---- MFMA: 4 K32-steps, B from LDS (XOR-swizzled granules), A from regs ----
#pragma unroll
    for (int ks = 0; ks < 4; ++ks) {
      const int gq = ((ks * 4 + lq) ^ lr) << 4;  // o&15 == lr for all B rows read
      short8 bfr[4];
#pragma unroll
      for (int nt = 0; nt < 4; ++nt) {
        const int o = wn * 64 + nt * 16 + lr;
        bfr[nt] = *(const short8*)(smem + cb + o * 256 + gq);
      }
#pragma unroll
      for (int mt = 0; mt < 2; ++mt)
#pragma unroll
        for (int nt = 0; nt < 4; ++nt)
          acc[mt][nt] = __builtin_amdgcn_mfma_f32_16x16x32_bf16(af[mt][ks], bfr[nt], acc[mt][nt], 0, 0, 0);
    }
    __syncthreads();  // vmcnt(0)+lgkmcnt(0) drain: stage(c+1)/x(c+1) landed,
                      // all reads of buf[cb] done -> next chunk may overwrite it
  };

  for (int c = 0; c < CPB; c += 2) {
    chunk_body(c, 0, xvA, xvB);
    if (c + 1 < CPB) chunk_body(c + 1, 32768, xvB, xvA);
  }

  // ---- epilogue: atomic accumulate across k-splits; bias on split 0 ----
#pragma unroll
  for (int nt = 0; nt < 4; ++nt) {
    const int col = wn * 64 + nt * 16 + lr;
    const float bv = (sp == 0) ? bias[col] : 0.0f;
#pragma unroll
    for (int mt = 0; mt < 2; ++mt) {
      const int rowb = b0 + wm * 32 + mt * 16 + lq * 4;
#pragma unroll
      for (int r = 0; r < 4; ++r)
        atomicAdd(out + (size_t)(rowb + r) * DOUT + col, acc[mt][nt][r] + bv);
    }
  }
}

// ---------------- safety-net naive kernel (only if ws too small) ----------------
__global__ void kan_naive(const float* __restrict__ x, const float* __restrict__ w,
                          const float* __restrict__ skw, const float* __restrict__ bias,
                          float* __restrict__ out) {
  const int b = blockIdx.x;
  const int o = threadIdx.x;
  float acc = bias[o];
  for (int i = 0; i < DIN; ++i) {
    float xv = x[(size_t)b * DIN + i];
    float t = fminf(fmaxf((xv + 3.0f) * (1.0f / 6.0f), 0.0f), 1.0f);
    float p = t * 15.0f;
    float fi = floorf(p);
    int i0 = (int)fi;
    int i1 = (i0 < 15) ? i0 + 1 : 15;
    float f = p - fi;
    const float* wr = &w[((size_t)o * DIN + i) * KK];
    acc += (1.0f - f) * wr[i0] + f * wr[i1] + xv * skw[(size_t)o * DIN + i];
  }
  out[(size_t)b * DOUT + o] = acc;
}

extern "C" void kernel_launch(void* const* d_in, const int* in_sizes, int n_in,
                              void* d_out, int out_size, void* d_ws, size_t ws_size,
                              hipStream_t stream) {
  const float* x    = (const float*)d_in[0];
  const float* w    = (const float*)d_in[1];  // (128, 512, 16) fp32
  const float* skw  = (const float*)d_in[2];  // (128, 512) fp32
  const float* bias = (const float*)d_in[3];  // (128,) fp32
  float* out = (float*)d_out;                 // (8192, 128) fp32

  const size_t need = (size_t)NCHUNK_TOT * CHUNK_BYTES;  // 2,228,224 B
  if (ws_size < need) {
    kan_naive<<<BTOT, DOUT, 0, stream>>>(x, w, skw, bias, out);
    return;
  }

  unsigned short* wpp = (unsigned short*)d_ws;

  hipMemsetAsync(d_out, 0, (size_t)out_size * sizeof(float), stream);
  build_wpp<<<NCHUNK_TOT * 2048 / 256, 256, 0, stream>>>(w, skw, wpp);
  kan_mfma<<<(BTOT / BM) * NSPL, 256, 0, stream>>>(x, wpp, bias, out);
}

// Round 2
// 110.245 us; speedup vs baseline: 1.1689x; 1.1689x over previous
//
#include <hip/hip_runtime.h>

typedef __attribute__((ext_vector_type(8))) short short8;
typedef __attribute__((ext_vector_type(4))) float f32x4;

#define DIN 512
#define DOUT 128
#define KK 16
#define BTOT 8192
#define KAUG (DIN * KK + DIN)        // 8704 augmented K (spline 8192 + skip 512)
#define NCHUNK_TOT (KAUG / 128)      // 68 chunks of BK=128
#define NSPL 4                       // split-K factor
#define CPB (NCHUNK_TOT / NSPL)      // 17 chunks per block
#define BM 128                       // b-rows per block
#define CHUNK_BYTES 32768            // W chunk: 128 o x 128 k x bf16
#define CT_BYTES 32768               // C tile: 128 b x 128 k x bf16
#define CBASE 65536                  // C buffers start after 2 W buffers
#define LDS_BYTES 131072             // W dbuf 64K + C dbuf 64K (dynamic)

// round-to-nearest-even fp32 -> bf16
__device__ static inline unsigned short f2bf(float x) {
  unsigned u = __builtin_bit_cast(unsigned, x);
  return (unsigned short)((u + 0x7FFFu + ((u >> 16) & 1u)) >> 16);
}

// async global->LDS, 16B per lane (dst = wave-uniform base, HW adds lane*16)
__device__ static inline void llds16(const char* g, char* l) {
  __builtin_amdgcn_global_load_lds(
      (const __attribute__((address_space(1))) unsigned int*)g,
      (__attribute__((address_space(3))) unsigned int*)l, 16, 0, 0);
}

// ---------------- prep: pack W_aug into swizzled bf16 chunk image ----------------
// (unchanged) W''[g][o][kcs] granules of 16B (8 bf16), kcs = kc ^ (o&15)
__global__ __launch_bounds__(256) void build_wpp(const float* __restrict__ w,
                                                 const float* __restrict__ sk,
                                                 unsigned short* __restrict__ wpp) {
  const int gi = blockIdx.x * 256 + threadIdx.x;
  const int g = gi >> 11;
  const int rem = gi & 2047;
  const int o = rem >> 4;
  const int kcs = rem & 15;
  const int kc = kcs ^ (o & 15);
  const int kglob = g * 128 + kc * 8;
  const float* src = (kglob < 8192) ? (w + (size_t)o * 8192 + kglob)
                                    : (sk + (size_t)o * 512 + (kglob - 8192));
  const float4 v0 = ((const float4*)src)[0];
  const float4 v1 = ((const float4*)src)[1];
  uint4 pk;
  pk.x = f2bf(v0.x) | ((unsigned)f2bf(v0.y) << 16);
  pk.y = f2bf(v0.z) | ((unsigned)f2bf(v0.w) << 16);
  pk.z = f2bf(v1.x) | ((unsigned)f2bf(v1.y) << 16);
  pk.w = f2bf(v1.z) | ((unsigned)f2bf(v1.w) << 16);
  ((uint4*)wpp)[gi] = pk;
}

// ---------------- main: 128x128 tile, 8 waves, full dbuf, 1 barrier/chunk ------
// grid 256 = 64 b-tiles x 4 k-splits (exactly 1 block/CU); block 512 (8 waves,
// wave grid 2m x 4n, wave-tile 64x32).
// Per chunk c: [prefetch x(c+1)] [stage W(c+1)->Wbuf^1] [MFMA(c) from Wbuf/Cbuf]
//   [build C(c+1)->Cbuf^1 via cheap LDS scatter] [__syncthreads].
// The barrier's vmcnt(0)/lgkmcnt(0) drain lands a full MFMA phase after the
// stage/prefetch were issued -> latency hidden; C-build amortized across 512
// threads (2 scatter-pairs each) instead of per-lane register assembly.
__global__ __launch_bounds__(512, 2) void kan_mfma(const float* __restrict__ x,
                                                   const unsigned short* __restrict__ wpp,
                                                   const float* __restrict__ bias,
                                                   float* __restrict__ out) {
  extern __shared__ __align__(16) char smem[];
  const int tid = threadIdx.x;
  const int bt = blockIdx.x >> 2;
  const int sp = blockIdx.x & 3;
  const int b0 = bt * BM;
  const int wid = tid >> 6, lane = tid & 63;
  const int lr = lane & 15, lq = lane >> 4;
  const int wm = wid >> 2, wn = wid & 3;   // 2 m-waves x 4 n-waves
  const int g0 = sp * CPB;

  f32x4 acc[4][2] = {};

  // ---- helpers ----
  auto stageW = [&](int g, int buf) {
    const char* gsrc = ((const char*)wpp) + (size_t)g * CHUNK_BYTES + wid * 4096 + lane * 16;
    char* ldst = smem + buf + wid * 4096;
#pragma unroll
    for (int it = 0; it < 4; ++it) llds16(gsrc + it * 1024, ldst + it * 1024);
  };

  // spline C-build: 1024 (row, i) pairs, 2 per thread; zero 2 granules + place
  // the 2 hat coefficients (round-0 proven numerics)
  auto buildSpline = [&](int cbuf, float xv0, float xv1) {
#pragma unroll
    for (int hh = 0; hh < 2; ++hh) {
      const int p = tid + hh * 512;
      const int bl = p >> 3, il = p & 7;
      const float xv = hh ? xv1 : xv0;
      float t = fminf(fmaxf((xv + 3.0f) * (1.0f / 6.0f), 0.0f), 1.0f);
      const float pos = t * 15.0f;
      int i0 = (int)pos;
      i0 = i0 > 14 ? 14 : i0;
      const float f = pos - (float)i0;
      char* row = smem + cbuf + bl * 256;
      const int swz = bl & 15;
      char* gA = row + (((il * 2) ^ swz) << 4);
      char* gB = row + (((il * 2 + 1) ^ swz) << 4);
      *(uint4*)gA = make_uint4(0, 0, 0, 0);
      *(uint4*)gB = make_uint4(0, 0, 0, 0);
      const unsigned short h0 = f2bf(1.0f - f);
      const unsigned short h1 = f2bf(f);
      const int i1 = i0 + 1;  // i0<=14 -> i1<=15
      *(unsigned short*)(((i0 & 8) ? gB : gA) + (i0 & 7) * 2) = h0;
      *(unsigned short*)(((i1 & 8) ? gB : gA) + (i1 & 7) * 2) = h1;
    }
  };

  // skip-augmented C-build: raw x in bf16, 4 granules/thread
  auto buildSkip = [&](int g, int cbuf) {
    const int ioff = (g - 64) * 128;
    const int bl = tid >> 2, q = tid & 3;
    const float* xr = x + (size_t)(b0 + bl) * DIN + ioff;
    char* row = smem + cbuf + bl * 256;
    const int swz = bl & 15;
#pragma unroll
    for (int gg = 0; gg < 4; ++gg) {
      const int kc = q * 4 + gg;
      const float4 v0 = ((const float4*)(xr + kc * 8))[0];
      const float4 v1 = ((const float4*)(xr + kc * 8))[1];
      uint4 pk;
      pk.x = f2bf(v0.x) | ((unsigned)f2bf(v0.y) << 16);
      pk.y = f2bf(v0.z) | ((unsigned)f2bf(v0.w) << 16);
      pk.z = f2bf(v1.x) | ((unsigned)f2bf(v1.y) << 16);
      pk.w = f2bf(v1.z) | ((unsigned)f2bf(v1.w) << 16);
      *(uint4*)(row + ((kc ^ swz) << 4)) = pk;
    }
  };

  // x values feeding buildSpline for chunk g (2 scalars per thread)
  auto loadX = [&](int g, float& a, float& b) {
    const int r0 = tid >> 3, il = tid & 7;
    a = x[(size_t)(b0 + r0) * DIN + g * 8 + il];
    b = x[(size_t)(b0 + 64 + r0) * DIN + g * 8 + il];
  };

  // ---- prologue: chunk 0 into parity-0 buffers (g0 always spline) ----
  stageW(g0, 0);
  {
    float a, b;
    loadX(g0, a, b);
    buildSpline(CBASE + 0, a, b);
  }
  __syncthreads();

  // ---- main loop ----
  for (int c = 0; c < CPB; ++c) {
    const int g = g0 + c;
    const int pb = (c & 1) << 15;       // current parity byte offset
    const int nb = pb ^ 32768;          // next parity
    const bool haveNext = (c + 1 < CPB);
    const int gn = g + 1;

    float xn0 = 0.0f, xn1 = 0.0f;
    if (haveNext && gn < 64) loadX(gn, xn0, xn1);   // issue early, consumed late
    if (haveNext) stageW(gn, nb);                   // in flight across MFMA phase

    // ---- MFMA: 4 K32-steps from parity-pb buffers ----
    const char* Wb = smem + pb;
    const char* Cb = smem + CBASE + pb;
#pragma unroll
    for (int ks = 0; ks < 4; ++ks) {
      const int swq = ((ks * 4 + lq) ^ lr) << 4;
      short8 af[4], bfr[2];
#pragma unroll
      for (int mt = 0; mt < 4; ++mt)
        af[mt] = *(const short8*)(Cb + (wm * 64 + mt * 16 + lr) * 256 + swq);
#pragma unroll
      for (int nt = 0; nt < 2; ++nt)
        bfr[nt] = *(const short8*)(Wb + (wn * 32 + nt * 16 + lr) * 256 + swq);
#pragma unroll
      for (int mt = 0; mt < 4; ++mt)
#pragma unroll
        for (int nt = 0; nt < 2; ++nt)
          acc[mt][nt] = __builtin_amdgcn_mfma_f32_16x16x32_bf16(af[mt], bfr[nt], acc[mt][nt], 0, 0, 0);
    }

    // ---- build C(c+1) into the other parity (safe: its readers finished at
    //      the barrier ending chunk c-1) ----
    if (haveNext) {
      if (gn < 64) buildSpline(CBASE + nb, xn0, xn1);
      else buildSkip(gn, CBASE + nb);
    }
    __syncthreads();  // drains stage(c+1) (issued ~full chunk ago) + C writes
  }

  // ---- epilogue: atomic accumulate across k-splits; bias on split 0 ----
#pragma unroll
  for (int nt = 0; nt < 2; ++nt) {
    const int col = wn * 32 + nt * 16 + lr;
    const float bv = (sp == 0) ? bias[col] : 0.0f;
#pragma unroll
    for (int mt = 0; mt < 4; ++mt) {
      const int rowb = b0 + wm * 64 + mt * 16 + lq * 4;
#pragma unroll
      for (int r = 0; r < 4; ++r)
        atomicAdd(out + (size_t)(rowb + r) * DOUT + col, acc[mt][nt][r] + bv);
    }
  }
}

// ---------------- safety-net naive kernel (only if ws too small) ----------------
__global__ void kan_naive(const float* __restrict__ x, const float* __restrict__ w,
                          const float* __restrict__ skw, const float* __restrict__ bias,
                          float* __restrict__ out) {
  const int b = blockIdx.x;
  const int o = threadIdx.x;
  float acc = bias[o];
  for (int i = 0; i < DIN; ++i) {
    float xv = x[(size_t)b * DIN + i];
    float t = fminf(fmaxf((xv + 3.0f) * (1.0f / 6.0f), 0.0f), 1.0f);
    float p = t * 15.0f;
    float fi = floorf(p);
    int i0 = (int)fi;
    int i1 = (i0 < 15) ? i0 + 1 : 15;
    float f = p - fi;
    const float* wr = &w[((size_t)o * DIN + i) * KK];
    acc += (1.0f - f) * wr[i0] + f * wr[i1] + xv * skw[(size_t)o * DIN + i];
  }
  out[(size_t)b * DOUT + o] = acc;
}

extern "C" void kernel_launch(void* const* d_in, const int* in_sizes, int n_in,
                              void* d_out, int out_size, void* d_ws, size_t ws_size,
                              hipStream_t stream) {
  const float* x    = (const float*)d_in[0];
  const float* w    = (const float*)d_in[1];  // (128, 512, 16) fp32
  const float* skw  = (const float*)d_in[2];  // (128, 512) fp32
  const float* bias = (const float*)d_in[3];  // (128,) fp32
  float* out = (float*)d_out;                 // (8192, 128) fp32

  // one-time: allow 128 KiB dynamic LDS for kan_mfma
  static bool lds_ok = []() {
    return hipFuncSetAttribute((const void*)kan_mfma,
                               hipFuncAttributeMaxDynamicSharedMemorySize,
                               LDS_BYTES) == hipSuccess;
  }();

  const size_t need = (size_t)NCHUNK_TOT * CHUNK_BYTES;  // 2,228,224 B
  if (ws_size < need || !lds_ok) {
    kan_naive<<<BTOT, DOUT, 0, stream>>>(x, w, skw, bias, out);
    return;
  }

  unsigned short* wpp = (unsigned short*)d_ws;

  hipMemsetAsync(d_out, 0, (size_t)out_size * sizeof(float), stream);
  build_wpp<<<NCHUNK_TOT * 2048 / 256, 256, 0, stream>>>(w, skw, wpp);
  kan_mfma<<<(BTOT / BM) * NSPL, 512, LDS_BYTES, stream>>>(x, wpp, bias, out);
}